// Round 3
// baseline (1089.165 us; speedup 1.0000x reference)
//
#include <hip/hip_runtime.h>

#define C_DIM 128
#define H_DIM 256
#define L_NUM 4

typedef __attribute__((ext_vector_type(8))) short bf16x8;
typedef __attribute__((ext_vector_type(4))) float f32x4;

__device__ __forceinline__ unsigned short f2bf(float f){
  unsigned u = __builtin_bit_cast(unsigned, f);
  u = u + 0x7FFFu + ((u >> 16) & 1u);   // round-to-nearest-even
  return (unsigned short)(u >> 16);
}
__device__ __forceinline__ float bf2f(unsigned short b){
  return __builtin_bit_cast(float, ((unsigned)b) << 16);
}

// ---------------- CSR build ----------------
__global__ void k_hist(const int* __restrict__ dst, int* __restrict__ cnt, int E){
  for (int e = blockIdx.x*blockDim.x + threadIdx.x; e < E; e += gridDim.x*blockDim.x)
    atomicAdd(cnt + dst[e], 1);
}

__global__ void k_scan_local(const int* __restrict__ cnt, int* __restrict__ rp,
                             int* __restrict__ bsum, int N){
  __shared__ int tmp[256];
  int t = threadIdx.x; int i = blockIdx.x*256 + t;
  int v = (i < N) ? cnt[i] : 0;
  tmp[t] = v; __syncthreads();
  for (int off = 1; off < 256; off <<= 1){
    int x = (t >= off) ? tmp[t-off] : 0; __syncthreads();
    tmp[t] += x; __syncthreads();
  }
  if (i < N) rp[i] = tmp[t] - v;              // exclusive within block
  if (t == 255) bsum[blockIdx.x] = tmp[t];
}

__global__ void k_scan_bsums(const int* __restrict__ bsum, int* __restrict__ boff, int nb){
  __shared__ int tmp[256];
  int t = threadIdx.x;
  int v = (t < nb) ? bsum[t] : 0;
  tmp[t] = v; __syncthreads();
  for (int off = 1; off < 256; off <<= 1){
    int x = (t >= off) ? tmp[t-off] : 0; __syncthreads();
    tmp[t] += x; __syncthreads();
  }
  if (t < nb) boff[t] = tmp[t] - v;           // exclusive
}

__global__ void k_scan_add(int* __restrict__ rp, const int* __restrict__ boff, int N, int E){
  int i = blockIdx.x*256 + threadIdx.x;
  if (i < N) rp[i] += boff[blockIdx.x];
  if (i == 0) rp[N] = E;
}

__global__ void k_scatter(const int* __restrict__ src, const int* __restrict__ dst,
                          const int* __restrict__ rp, int* __restrict__ cnt,
                          int* __restrict__ csrc, int E){
  for (int e = blockIdx.x*blockDim.x + threadIdx.x; e < E; e += gridDim.x*blockDim.x){
    int d = dst[e];
    int pos = rp[d] + atomicAdd(cnt + d, 1);
    csrc[pos] = src[e];
  }
}

// ---------------- weight transpose+convert ----------------
__global__ void k_wconv(const float* __restrict__ W1, const float* __restrict__ W2,
                        unsigned short* __restrict__ W1t, unsigned short* __restrict__ W2t){
  int i = blockIdx.x*blockDim.x + threadIdx.x;
  if (i >= L_NUM*C_DIM*H_DIM) return;
  int l = i >> 15, r = i & 32767;
  { int k = r >> 8, n = r & 255;  W1t[l*32768 + n*128 + k] = f2bf(W1[i]); }
  { int k = r >> 7, n = r & 127;  W2t[l*32768 + n*256 + k] = f2bf(W2[i]); }
}

// ---------------- layer-0 per-channel partial stats (non-atomic) ----------------
// part[b*256 + c] = sum, part[b*256 + 128 + c] = sumsq, over rows [b*128, b*128+128)
__global__ void k_stat0(const float* __restrict__ X, float* __restrict__ part, int N){
  int t = threadIdx.x; int c = t & 127; int half = t >> 7;
  int r0 = blockIdx.x*128, rend = min(r0 + 128, N);
  float s = 0.f, s2 = 0.f;
  for (int r = r0 + half; r < rend; r += 2){
    float v = X[r*C_DIM + c]; s += v; s2 += v*v;
  }
  __shared__ float a1[256], a2[256];
  a1[t] = s; a2[t] = s2; __syncthreads();
  if (t < 128){
    part[blockIdx.x*256 + c] = a1[t] + a1[t+128];
    part[blockIdx.x*256 + 128 + c] = a2[t] + a2[t+128];
  }
}

// ---------------- graph norm coef (reduces per-block partials) ----------------
__global__ void k_gn_coef(const float* __restrict__ part, int nb,
                          const float* __restrict__ gw, const float* __restrict__ gb,
                          const float* __restrict__ ga, float* __restrict__ coef, int N){
  int t = threadIdx.x;   // 256: t<128 sums, t>=128 sumsqs
  float acc = 0.f;
  for (int b = 0; b < nb; ++b) acc += part[b*256 + t];
  __shared__ float sh[256];
  sh[t] = acc; __syncthreads();
  if (t < 128){
    float inv = 1.f/(float)N;
    float mean = sh[t]*inv;
    float am = ga[t]*mean;
    float var = sh[128+t]*inv - 2.f*am*mean + am*am;   // E[(x - a*mean)^2]
    float scale = gw[t] * rsqrtf(var + 1e-5f);
    coef[t] = scale;
    coef[128+t] = gb[t] - scale*am;
  }
}

// ---------------- g = relu(affine(x)) in bf16 ----------------
__global__ void k_gpre(const float* __restrict__ X, const float* __restrict__ coef,
                       unsigned* __restrict__ G2, int total4){
  int i = blockIdx.x*blockDim.x + threadIdx.x;
  if (i >= total4) return;
  int c4 = i & 31;
  float4 x = ((const float4*)X)[i];
  float4 A = ((const float4*)coef)[c4];
  float4 B = ((const float4*)coef)[32 + c4];
  float o0 = fmaxf(A.x*x.x + B.x, 0.f);
  float o1 = fmaxf(A.y*x.y + B.y, 0.f);
  float o2 = fmaxf(A.z*x.z + B.z, 0.f);
  float o3 = fmaxf(A.w*x.w + B.w, 0.f);
  uint2 pk = make_uint2((unsigned)f2bf(o0) | ((unsigned)f2bf(o1) << 16),
                        (unsigned)f2bf(o2) | ((unsigned)f2bf(o3) << 16));
  ((uint2*)G2)[i] = pk;
}

// ---------------- softmax aggregation, max-free (z >= 0, bounded; clamp for safety) --------
__global__ void k_agg(const unsigned* __restrict__ G, const int* __restrict__ rp,
                      const int* __restrict__ csrc, const float* __restrict__ tptr, int l,
                      unsigned short* __restrict__ U, int N){
  int wave = threadIdx.x >> 6, lane = threadIdx.x & 63;
  int n = blockIdx.x*4 + wave;
  if (n >= N) return;
  float tv = tptr[l];
  int jb = rp[n], je = rp[n+1];
  float d0 = 0.f, d1 = 0.f, s0 = 0.f, s1 = 0.f;

  #define EDGE(uu) { \
    float msg0 = bf2f((unsigned short)((uu) & 0xffff)) + 1e-7f; \
    float msg1 = bf2f((unsigned short)((uu) >> 16)) + 1e-7f; \
    float e0 = __expf(fminf(tv*msg0, 60.f)); \
    float e1 = __expf(fminf(tv*msg1, 60.f)); \
    d0 += e0; d1 += e1; s0 += msg0*e0; s1 += msg1*e1; }

  int j = jb;
  for (; j + 3 < je; j += 4){
    int i0 = csrc[j], i1 = csrc[j+1], i2 = csrc[j+2], i3 = csrc[j+3];
    unsigned u0 = G[i0*64 + lane];
    unsigned u1 = G[i1*64 + lane];
    unsigned u2 = G[i2*64 + lane];
    unsigned u3 = G[i3*64 + lane];
    EDGE(u0); EDGE(u1); EDGE(u2); EDGE(u3);
  }
  for (; j < je; ++j){
    unsigned u = G[csrc[j]*64 + lane];
    EDGE(u);
  }
  #undef EDGE

  unsigned uo = G[n*64 + lane];
  float g0 = bf2f((unsigned short)(uo & 0xffff));
  float g1 = bf2f((unsigned short)(uo >> 16));
  float u0 = s0/(d0 + 1e-16f) + g0;
  float u1 = s1/(d1 + 1e-16f) + g1;
  unsigned pk = (unsigned)f2bf(u0) | ((unsigned)f2bf(u1) << 16);
  *(unsigned*)(U + n*C_DIM + lane*2) = pk;
}

// ---------------- GEMM1: h1(bf16) = U(bf16)[M,128] @ W1t^T + b1 ; per-block LN partials ----
__global__ void k_gemm1(const unsigned short* __restrict__ A, const unsigned short* __restrict__ Bt,
                        const float* __restrict__ b1, unsigned short* __restrict__ H1,
                        float* __restrict__ part, int M){
  __shared__ __align__(16) char smem[64*256];   // 64 rows x 128 bf16 (256B rows), swizzled
  __shared__ float rbuf[8];
  const int tid = threadIdx.x;
  const int m0 = blockIdx.x * 64;
  const int wave = tid >> 6, lane = tid & 63;
  const int lr = lane & 15, lc = lane >> 4;

  bf16x8 bf[4][4];
  #pragma unroll
  for (int nf = 0; nf < 4; ++nf){
    int n = wave*64 + nf*16 + lr;
    #pragma unroll
    for (int ks = 0; ks < 4; ++ks)
      bf[nf][ks] = *(const bf16x8*)(Bt + n*128 + ks*32 + lc*8);
  }
  #pragma unroll
  for (int p = 0; p < 4; ++p){
    int idx = p*256 + tid;
    int row = idx >> 4, ch = idx & 15;
    int r = m0 + row;
    uint4 v = make_uint4(0u,0u,0u,0u);
    if (r < M) v = *(const uint4*)(A + r*128 + ch*8);
    int o = (row*256 + ch*16) ^ ((row & 7) << 4);
    *(uint4*)(smem + o) = v;
  }
  __syncthreads();

  f32x4 acc[4][4] = {};
  #pragma unroll
  for (int ks = 0; ks < 4; ++ks){
    bf16x8 a[4];
    #pragma unroll
    for (int mf = 0; mf < 4; ++mf){
      int row = mf*16 + lr;
      int o = (row*256 + ks*64 + lc*16) ^ ((row & 7) << 4);
      a[mf] = *(const bf16x8*)(smem + o);
    }
    #pragma unroll
    for (int mf = 0; mf < 4; ++mf)
      #pragma unroll
      for (int nf = 0; nf < 4; ++nf)
        acc[mf][nf] = __builtin_amdgcn_mfma_f32_16x16x32_bf16(a[mf], bf[nf][ks], acc[mf][nf], 0, 0, 0);
  }

  float s1 = 0.f, s2 = 0.f;
  #pragma unroll
  for (int mf = 0; mf < 4; ++mf){
    #pragma unroll
    for (int j = 0; j < 4; ++j){
      int r = m0 + mf*16 + lc*4 + j;
      if (r < M){
        #pragma unroll
        for (int nf = 0; nf < 4; ++nf){
          int col = wave*64 + nf*16 + lr;
          float v = acc[mf][nf][j] + b1[col];
          H1[r*H_DIM + col] = f2bf(v);
          s1 += v; s2 += v*v;
        }
      }
    }
  }
  #pragma unroll
  for (int o = 32; o; o >>= 1){ s1 += __shfl_down(s1, o); s2 += __shfl_down(s2, o); }
  if (lane == 0){ rbuf[wave] = s1; rbuf[4 + wave] = s2; }
  __syncthreads();
  if (tid == 0)
    part[blockIdx.x*2]     = rbuf[0]+rbuf[1]+rbuf[2]+rbuf[3];
  if (tid == 1)
    part[blockIdx.x*2 + 1] = rbuf[4]+rbuf[5]+rbuf[6]+rbuf[7];
}

__global__ void k_ln_coef(const float* __restrict__ part, int nb,
                          const float* __restrict__ lnw, const float* __restrict__ lnb,
                          float* __restrict__ coef, int M){
  __shared__ float s1s[256], s2s[256];
  int t = threadIdx.x;
  float s1 = 0.f, s2 = 0.f;
  for (int i = t; i < nb; i += 256){ s1 += part[2*i]; s2 += part[2*i+1]; }
  s1s[t] = s1; s2s[t] = s2; __syncthreads();
  for (int off = 128; off; off >>= 1){
    if (t < off){ s1s[t] += s1s[t+off]; s2s[t] += s2s[t+off]; }
    __syncthreads();
  }
  double NH = (double)M * (double)H_DIM;
  double mean = (double)s1s[0] / NH;
  double var = (double)s2s[0] / NH - mean*mean;
  double sd = sqrt(var > 0.0 ? var : 0.0);
  float denom = (float)sd + 1e-5f;
  float wv = lnw[t] / denom;
  coef[t] = wv;
  coef[256 + t] = lnb[t] - (float)mean * wv;
}

// ---------------- GEMM2: x += relu(affine(H1))(bf16) @ W2t^T + b2 ; next-layer GN partials --
__global__ void k_gemm2(const unsigned short* __restrict__ H1, const float* __restrict__ lncoef,
                        const unsigned short* __restrict__ Bt, const float* __restrict__ b2,
                        float* __restrict__ X, float* __restrict__ part, int M){
  __shared__ __align__(16) char smem[64*512];   // 64 rows x 256 bf16 (512B rows), swizzled
  const int tid = threadIdx.x;
  const int m0 = blockIdx.x * 64;
  const int wave = tid >> 6, lane = tid & 63;
  const int lr = lane & 15, lc = lane >> 4;
  const float* colw = lncoef;
  const float* colb = lncoef + 256;

  bf16x8 bf[2][8];
  #pragma unroll
  for (int nf = 0; nf < 2; ++nf){
    int n = wave*32 + nf*16 + lr;
    #pragma unroll
    for (int ks = 0; ks < 8; ++ks)
      bf[nf][ks] = *(const bf16x8*)(Bt + n*256 + ks*32 + lc*8);
  }
  #pragma unroll
  for (int p = 0; p < 8; ++p){
    int idx = (p*256 + tid)*8;
    int row = idx >> 8, col = idx & 255;
    int r = m0 + row;
    uint4 v = make_uint4(0u,0u,0u,0u);
    if (r < M) v = *(const uint4*)(H1 + r*H_DIM + col);
    unsigned short hb[8] = {(unsigned short)(v.x&0xffff),(unsigned short)(v.x>>16),
                            (unsigned short)(v.y&0xffff),(unsigned short)(v.y>>16),
                            (unsigned short)(v.z&0xffff),(unsigned short)(v.z>>16),
                            (unsigned short)(v.w&0xffff),(unsigned short)(v.w>>16)};
    unsigned outp[4];
    #pragma unroll
    for (int q = 0; q < 4; ++q){
      float f0 = fmaxf(colw[col+2*q]  *bf2f(hb[2*q])   + colb[col+2*q],   0.f);
      float f1 = fmaxf(colw[col+2*q+1]*bf2f(hb[2*q+1]) + colb[col+2*q+1], 0.f);
      outp[q] = (unsigned)f2bf(f0) | ((unsigned)f2bf(f1) << 16);
    }
    int o = (row*512 + col*2) ^ ((row & 7) << 4);
    *(uint4*)(smem + o) = make_uint4(outp[0],outp[1],outp[2],outp[3]);
  }
  __syncthreads();

  f32x4 acc[4][2] = {};
  #pragma unroll
  for (int ks = 0; ks < 8; ++ks){
    bf16x8 a[4];
    #pragma unroll
    for (int mf = 0; mf < 4; ++mf){
      int row = mf*16 + lr;
      int o = (row*512 + ks*64 + lc*16) ^ ((row & 7) << 4);
      a[mf] = *(const bf16x8*)(smem + o);
    }
    #pragma unroll
    for (int mf = 0; mf < 4; ++mf)
      #pragma unroll
      for (int nf = 0; nf < 2; ++nf)
        acc[mf][nf] = __builtin_amdgcn_mfma_f32_16x16x32_bf16(a[mf], bf[nf][ks], acc[mf][nf], 0, 0, 0);
  }

  float sA[2] = {0.f, 0.f}, sB[2] = {0.f, 0.f};   // per-nf column partial sum / sumsq
  #pragma unroll
  for (int mf = 0; mf < 4; ++mf){
    #pragma unroll
    for (int j = 0; j < 4; ++j){
      int r = m0 + mf*16 + lc*4 + j;
      if (r < M){
        #pragma unroll
        for (int nf = 0; nf < 2; ++nf){
          int col = wave*32 + nf*16 + lr;
          float v = X[r*C_DIM + col] + acc[mf][nf][j] + b2[col];
          X[r*C_DIM + col] = v;
          sA[nf] += v; sB[nf] += v*v;
        }
      }
    }
  }
  // reduce across the 4 lanes sharing lr (lc = 0..3): lanes lr, lr+16, lr+32, lr+48
  #pragma unroll
  for (int nf = 0; nf < 2; ++nf){
    sA[nf] += __shfl_xor(sA[nf], 16); sA[nf] += __shfl_xor(sA[nf], 32);
    sB[nf] += __shfl_xor(sB[nf], 16); sB[nf] += __shfl_xor(sB[nf], 32);
  }
  if (lane < 16){
    #pragma unroll
    for (int nf = 0; nf < 2; ++nf){
      int col = wave*32 + nf*16 + lr;
      part[blockIdx.x*256 + col] = sA[nf];
      part[blockIdx.x*256 + 128 + col] = sB[nf];
    }
  }
}

// ---------------- final linear ----------------
__global__ void k_final(const float* __restrict__ X, const float* __restrict__ lw,
                        const float* __restrict__ lb, float* __restrict__ out, int N){
  int wave = threadIdx.x >> 6, lane = threadIdx.x & 63;
  int n = blockIdx.x*4 + wave;
  if (n >= N) return;
  float2 v = *(const float2*)(X + n*C_DIM + lane*2);
  float2 w = *(const float2*)(lw + lane*2);
  float s = v.x*w.x + v.y*w.y;
  #pragma unroll
  for (int o = 32; o; o >>= 1) s += __shfl_down(s, o);
  if (lane == 0) out[n] = s + lb[0];
}

extern "C" void kernel_launch(void* const* d_in, const int* in_sizes, int n_in,
                              void* d_out, int out_size, void* d_ws, size_t ws_size,
                              hipStream_t stream){
  const float* x    = (const float*)d_in[0];
  const int*   src  = (const int*)d_in[1];
  const int*   dst  = (const int*)d_in[2];
  const float* W1   = (const float*)d_in[3];
  const float* b1   = (const float*)d_in[4];
  const float* lnw  = (const float*)d_in[5];
  const float* lnb  = (const float*)d_in[6];
  const float* W2   = (const float*)d_in[7];
  const float* b2   = (const float*)d_in[8];
  const float* tpt  = (const float*)d_in[9];
  const float* gnw  = (const float*)d_in[10];
  const float* gnb  = (const float*)d_in[11];
  const float* gna  = (const float*)d_in[12];
  const float* linw = (const float*)d_in[13];
  const float* linb = (const float*)d_in[14];
  (void)n_in; (void)out_size; (void)ws_size;
  const int N = in_sizes[0] / C_DIM;
  const int E = in_sizes[1];
  float* out = (float*)d_out;

  const int gmw = (N + 63)/64;          // gemm blocks (64 rows each)
  const int S0  = (N + 127)/128;        // stat0 blocks

  char* wsp = (char*)d_ws; size_t off = 0;
  auto alloc = [&](size_t b)->char*{ char* p = wsp + off; off += (b + 255) & ~(size_t)255; return p; };
  int* cnt          = (int*)alloc((size_t)N*4);
  int* rp           = (int*)alloc((size_t)(N+1)*4);
  int* bsum         = (int*)alloc(1024);
  int* boff         = (int*)alloc(1024);
  float* gncoef     = (float*)alloc(1024);
  float* lncoef     = (float*)alloc(2048);
  float* lnpart     = (float*)alloc((size_t)gmw*2*4);
  float* part       = (float*)alloc((size_t)gmw*256*4);   // per-block GN partials
  int* csrc         = (int*)alloc((size_t)E*4);
  unsigned short* W1t = (unsigned short*)alloc((size_t)L_NUM*C_DIM*H_DIM*2);
  unsigned short* W2t = (unsigned short*)alloc((size_t)L_NUM*C_DIM*H_DIM*2);
  unsigned* g       = (unsigned*)alloc((size_t)N*C_DIM*2);   // bf16 [N][128]
  unsigned short* U = (unsigned short*)alloc((size_t)N*C_DIM*2);
  unsigned short* h1 = (unsigned short*)alloc((size_t)N*H_DIM*2);
  float* xc         = (float*)alloc((size_t)N*C_DIM*4);

  const int SB = (N + 255)/256;
  hipMemsetAsync(cnt, 0, (size_t)N*4, stream);
  k_hist<<<1024, 256, 0, stream>>>(dst, cnt, E);
  k_scan_local<<<SB, 256, 0, stream>>>(cnt, rp, bsum, N);
  k_scan_bsums<<<1, 256, 0, stream>>>(bsum, boff, SB);
  k_scan_add<<<SB, 256, 0, stream>>>(rp, boff, N, E);
  hipMemsetAsync(cnt, 0, (size_t)N*4, stream);
  k_scatter<<<1024, 256, 0, stream>>>(src, dst, rp, cnt, csrc, E);
  k_wconv<<<(L_NUM*C_DIM*H_DIM + 255)/256, 256, 0, stream>>>(W1, W2, W1t, W2t);
  hipMemcpyAsync(xc, x, (size_t)N*C_DIM*4, hipMemcpyDeviceToDevice, stream);
  k_stat0<<<S0, 256, 0, stream>>>(x, part, N);

  for (int l = 0; l < L_NUM; ++l){
    int nb = (l == 0) ? S0 : gmw;
    k_gn_coef<<<1, 256, 0, stream>>>(part, nb, gnw + l*C_DIM, gnb + l*C_DIM, gna + l*C_DIM, gncoef, N);
    k_gpre<<<(N*32 + 255)/256, 256, 0, stream>>>(xc, gncoef, g, N*32);
    k_agg<<<(N + 3)/4, 256, 0, stream>>>(g, rp, csrc, tpt, l, U, N);
    k_gemm1<<<gmw, 256, 0, stream>>>(U, W1t + (size_t)l*C_DIM*H_DIM, b1 + l*H_DIM, h1, lnpart, N);
    k_ln_coef<<<1, 256, 0, stream>>>(lnpart, gmw, lnw + l*H_DIM, lnb + l*H_DIM, lncoef, N);
    k_gemm2<<<gmw, 256, 0, stream>>>(h1, lncoef, W2t + (size_t)l*C_DIM*H_DIM, b2 + l*C_DIM, xc, part, N);
  }
  k_final<<<(N + 3)/4, 256, 0, stream>>>(xc, linw, linb, out, N);
}

// Round 4
// 479.150 us; speedup vs baseline: 2.2731x; 2.2731x over previous
//
#include <hip/hip_runtime.h>

#define C_DIM 128
#define H_DIM 256
#define L_NUM 4

typedef __attribute__((ext_vector_type(8))) short bf16x8;
typedef __attribute__((ext_vector_type(4))) float f32x4;

__device__ __forceinline__ unsigned short f2bf(float f){
  unsigned u = __builtin_bit_cast(unsigned, f);
  u = u + 0x7FFFu + ((u >> 16) & 1u);   // round-to-nearest-even
  return (unsigned short)(u >> 16);
}
__device__ __forceinline__ float bf2f(unsigned short b){
  return __builtin_bit_cast(float, ((unsigned)b) << 16);
}

// ---------------- CSR build ----------------
__global__ void k_hist(const int* __restrict__ dst, int* __restrict__ cnt, int E){
  for (int e = blockIdx.x*blockDim.x + threadIdx.x; e < E; e += gridDim.x*blockDim.x)
    atomicAdd(cnt + dst[e], 1);
}

__global__ void k_scan_local(const int* __restrict__ cnt, int* __restrict__ rp,
                             int* __restrict__ bsum, int N){
  __shared__ int tmp[256];
  int t = threadIdx.x; int i = blockIdx.x*256 + t;
  int v = (i < N) ? cnt[i] : 0;
  tmp[t] = v; __syncthreads();
  for (int off = 1; off < 256; off <<= 1){
    int x = (t >= off) ? tmp[t-off] : 0; __syncthreads();
    tmp[t] += x; __syncthreads();
  }
  if (i < N) rp[i] = tmp[t] - v;              // exclusive within block
  if (t == 255) bsum[blockIdx.x] = tmp[t];
}

__global__ void k_scan_bsums(const int* __restrict__ bsum, int* __restrict__ boff, int nb){
  __shared__ int tmp[256];
  int t = threadIdx.x;
  int v = (t < nb) ? bsum[t] : 0;
  tmp[t] = v; __syncthreads();
  for (int off = 1; off < 256; off <<= 1){
    int x = (t >= off) ? tmp[t-off] : 0; __syncthreads();
    tmp[t] += x; __syncthreads();
  }
  if (t < nb) boff[t] = tmp[t] - v;           // exclusive
}

__global__ void k_scan_add(int* __restrict__ rp, const int* __restrict__ boff, int N, int E){
  int i = blockIdx.x*256 + threadIdx.x;
  if (i < N) rp[i] += boff[blockIdx.x];
  if (i == 0) rp[N] = E;
}

__global__ void k_scatter(const int* __restrict__ src, const int* __restrict__ dst,
                          const int* __restrict__ rp, int* __restrict__ cnt,
                          int* __restrict__ csrc, int E){
  for (int e = blockIdx.x*blockDim.x + threadIdx.x; e < E; e += gridDim.x*blockDim.x){
    int d = dst[e];
    int pos = rp[d] + atomicAdd(cnt + d, 1);
    csrc[pos] = src[e];
  }
}

// ---------------- weight transpose+convert ----------------
__global__ void k_wconv(const float* __restrict__ W1, const float* __restrict__ W2,
                        unsigned short* __restrict__ W1t, unsigned short* __restrict__ W2t){
  int i = blockIdx.x*blockDim.x + threadIdx.x;
  if (i >= L_NUM*C_DIM*H_DIM) return;
  int l = i >> 15, r = i & 32767;
  { int k = r >> 8, n = r & 255;  W1t[l*32768 + n*128 + k] = f2bf(W1[i]); }
  { int k = r >> 7, n = r & 127;  W2t[l*32768 + n*256 + k] = f2bf(W2[i]); }
}

// ---------------- layer-0 per-channel partial stats (column-major part[stat][NB]) --------
__global__ void k_stat0(const float* __restrict__ X, float* __restrict__ part, int NB, int N){
  int t = threadIdx.x; int c = t & 127; int half = t >> 7;
  int r0 = blockIdx.x*128, rend = min(r0 + 128, N);
  float s = 0.f, s2 = 0.f;
  for (int r = r0 + half; r < rend; r += 2){
    float v = X[r*C_DIM + c]; s += v; s2 += v*v;
  }
  __shared__ float a1[256], a2[256];
  a1[t] = s; a2[t] = s2; __syncthreads();
  if (t < 128){
    part[t*NB + blockIdx.x]       = a1[t] + a1[t+128];
    part[(128+t)*NB + blockIdx.x] = a2[t] + a2[t+128];
  }
}

// ---------------- graph norm: reduce partials + coef, one block per channel ----------------
__global__ void k_gn_coef(const float* __restrict__ part, int NB, int nb,
                          const float* __restrict__ gw, const float* __restrict__ gb,
                          const float* __restrict__ ga, float* __restrict__ coef, int N){
  int c = blockIdx.x;       // 0..127
  int t = threadIdx.x;      // 256
  float s = 0.f, s2 = 0.f;
  for (int i = t; i < nb; i += 256){
    s  += part[c*NB + i];
    s2 += part[(128+c)*NB + i];
  }
  __shared__ float sh1[256], sh2[256];
  sh1[t] = s; sh2[t] = s2; __syncthreads();
  for (int off = 128; off; off >>= 1){
    if (t < off){ sh1[t] += sh1[t+off]; sh2[t] += sh2[t+off]; }
    __syncthreads();
  }
  if (t == 0){
    float inv = 1.f/(float)N;
    float mean = sh1[0]*inv;
    float am = ga[c]*mean;
    float var = sh2[0]*inv - 2.f*am*mean + am*am;   // E[(x - a*mean)^2]
    float scale = gw[c] * rsqrtf(var + 1e-5f);
    coef[c] = scale;
    coef[128+c] = gb[c] - scale*am;
  }
}

// ---------------- g = relu(affine(x)) in bf16 ----------------
__global__ void k_gpre(const float* __restrict__ X, const float* __restrict__ coef,
                       unsigned* __restrict__ G2, int total4){
  int i = blockIdx.x*blockDim.x + threadIdx.x;
  if (i >= total4) return;
  int c4 = i & 31;
  float4 x = ((const float4*)X)[i];
  float4 A = ((const float4*)coef)[c4];
  float4 B = ((const float4*)coef)[32 + c4];
  float o0 = fmaxf(A.x*x.x + B.x, 0.f);
  float o1 = fmaxf(A.y*x.y + B.y, 0.f);
  float o2 = fmaxf(A.z*x.z + B.z, 0.f);
  float o3 = fmaxf(A.w*x.w + B.w, 0.f);
  uint2 pk = make_uint2((unsigned)f2bf(o0) | ((unsigned)f2bf(o1) << 16),
                        (unsigned)f2bf(o2) | ((unsigned)f2bf(o3) << 16));
  ((uint2*)G2)[i] = pk;
}

// ---------------- softmax aggregation, max-free (z >= 0, bounded; clamp for safety) --------
__global__ void k_agg(const unsigned* __restrict__ G, const int* __restrict__ rp,
                      const int* __restrict__ csrc, const float* __restrict__ tptr, int l,
                      unsigned short* __restrict__ U, int N){
  int wave = threadIdx.x >> 6, lane = threadIdx.x & 63;
  int n = blockIdx.x*4 + wave;
  if (n >= N) return;
  float tv = tptr[l];
  int jb = rp[n], je = rp[n+1];
  float d0 = 0.f, d1 = 0.f, s0 = 0.f, s1 = 0.f;

  #define EDGE(uu) { \
    float msg0 = bf2f((unsigned short)((uu) & 0xffff)) + 1e-7f; \
    float msg1 = bf2f((unsigned short)((uu) >> 16)) + 1e-7f; \
    float e0 = __expf(fminf(tv*msg0, 60.f)); \
    float e1 = __expf(fminf(tv*msg1, 60.f)); \
    d0 += e0; d1 += e1; s0 += msg0*e0; s1 += msg1*e1; }

  int j = jb;
  for (; j + 3 < je; j += 4){
    int i0 = csrc[j], i1 = csrc[j+1], i2 = csrc[j+2], i3 = csrc[j+3];
    unsigned u0 = G[i0*64 + lane];
    unsigned u1 = G[i1*64 + lane];
    unsigned u2 = G[i2*64 + lane];
    unsigned u3 = G[i3*64 + lane];
    EDGE(u0); EDGE(u1); EDGE(u2); EDGE(u3);
  }
  for (; j < je; ++j){
    unsigned u = G[csrc[j]*64 + lane];
    EDGE(u);
  }
  #undef EDGE

  unsigned uo = G[n*64 + lane];
  float g0 = bf2f((unsigned short)(uo & 0xffff));
  float g1 = bf2f((unsigned short)(uo >> 16));
  float u0 = s0/(d0 + 1e-16f) + g0;
  float u1 = s1/(d1 + 1e-16f) + g1;
  unsigned pk = (unsigned)f2bf(u0) | ((unsigned)f2bf(u1) << 16);
  *(unsigned*)(U + n*C_DIM + lane*2) = pk;
}

// ---------------- GEMM1: h1(bf16) = U(bf16)[M,128] @ W1t^T + b1 ; per-block LN partials ----
__global__ void k_gemm1(const unsigned short* __restrict__ A, const unsigned short* __restrict__ Bt,
                        const float* __restrict__ b1, unsigned short* __restrict__ H1,
                        float* __restrict__ part, int M){
  __shared__ __align__(16) char smem[64*256];   // 64 rows x 128 bf16 (256B rows), swizzled
  __shared__ float rbuf[8];
  const int tid = threadIdx.x;
  const int m0 = blockIdx.x * 64;
  const int wave = tid >> 6, lane = tid & 63;
  const int lr = lane & 15, lc = lane >> 4;

  bf16x8 bf[4][4];
  #pragma unroll
  for (int nf = 0; nf < 4; ++nf){
    int n = wave*64 + nf*16 + lr;
    #pragma unroll
    for (int ks = 0; ks < 4; ++ks)
      bf[nf][ks] = *(const bf16x8*)(Bt + n*128 + ks*32 + lc*8);
  }
  #pragma unroll
  for (int p = 0; p < 4; ++p){
    int idx = p*256 + tid;
    int row = idx >> 4, ch = idx & 15;
    int r = m0 + row;
    uint4 v = make_uint4(0u,0u,0u,0u);
    if (r < M) v = *(const uint4*)(A + r*128 + ch*8);
    int o = (row*256 + ch*16) ^ ((row & 7) << 4);
    *(uint4*)(smem + o) = v;
  }
  __syncthreads();

  f32x4 acc[4][4] = {};
  #pragma unroll
  for (int ks = 0; ks < 4; ++ks){
    bf16x8 a[4];
    #pragma unroll
    for (int mf = 0; mf < 4; ++mf){
      int row = mf*16 + lr;
      int o = (row*256 + ks*64 + lc*16) ^ ((row & 7) << 4);
      a[mf] = *(const bf16x8*)(smem + o);
    }
    #pragma unroll
    for (int mf = 0; mf < 4; ++mf)
      #pragma unroll
      for (int nf = 0; nf < 4; ++nf)
        acc[mf][nf] = __builtin_amdgcn_mfma_f32_16x16x32_bf16(a[mf], bf[nf][ks], acc[mf][nf], 0, 0, 0);
  }

  float s1 = 0.f, s2 = 0.f;
  #pragma unroll
  for (int mf = 0; mf < 4; ++mf){
    #pragma unroll
    for (int j = 0; j < 4; ++j){
      int r = m0 + mf*16 + lc*4 + j;
      if (r < M){
        #pragma unroll
        for (int nf = 0; nf < 4; ++nf){
          int col = wave*64 + nf*16 + lr;
          float v = acc[mf][nf][j] + b1[col];
          H1[r*H_DIM + col] = f2bf(v);
          s1 += v; s2 += v*v;
        }
      }
    }
  }
  #pragma unroll
  for (int o = 32; o; o >>= 1){ s1 += __shfl_down(s1, o); s2 += __shfl_down(s2, o); }
  if (lane == 0){ rbuf[wave] = s1; rbuf[4 + wave] = s2; }
  __syncthreads();
  if (tid == 0)
    part[blockIdx.x*2]     = rbuf[0]+rbuf[1]+rbuf[2]+rbuf[3];
  if (tid == 1)
    part[blockIdx.x*2 + 1] = rbuf[4]+rbuf[5]+rbuf[6]+rbuf[7];
}

__global__ void k_ln_coef(const float* __restrict__ part, int nb,
                          const float* __restrict__ lnw, const float* __restrict__ lnb,
                          float* __restrict__ coef, int M){
  __shared__ float s1s[256], s2s[256];
  int t = threadIdx.x;
  float s1 = 0.f, s2 = 0.f;
  for (int i = t; i < nb; i += 256){ s1 += part[2*i]; s2 += part[2*i+1]; }
  s1s[t] = s1; s2s[t] = s2; __syncthreads();
  for (int off = 128; off; off >>= 1){
    if (t < off){ s1s[t] += s1s[t+off]; s2s[t] += s2s[t+off]; }
    __syncthreads();
  }
  double NH = (double)M * (double)H_DIM;
  double mean = (double)s1s[0] / NH;
  double var = (double)s2s[0] / NH - mean*mean;
  double sd = sqrt(var > 0.0 ? var : 0.0);
  float denom = (float)sd + 1e-5f;
  float wv = lnw[t] / denom;
  coef[t] = wv;
  coef[256 + t] = lnb[t] - (float)mean * wv;
}

// ---------------- GEMM2: x += relu(affine(H1))(bf16) @ W2t^T + b2 ; next-layer GN partials --
__global__ void k_gemm2(const unsigned short* __restrict__ H1, const float* __restrict__ lncoef,
                        const unsigned short* __restrict__ Bt, const float* __restrict__ b2,
                        float* __restrict__ X, float* __restrict__ part, int NB, int M){
  __shared__ __align__(16) char smem[64*512];   // 64 rows x 256 bf16 (512B rows), swizzled
  const int tid = threadIdx.x;
  const int m0 = blockIdx.x * 64;
  const int wave = tid >> 6, lane = tid & 63;
  const int lr = lane & 15, lc = lane >> 4;
  const float* colw = lncoef;
  const float* colb = lncoef + 256;

  bf16x8 bf[2][8];
  #pragma unroll
  for (int nf = 0; nf < 2; ++nf){
    int n = wave*32 + nf*16 + lr;
    #pragma unroll
    for (int ks = 0; ks < 8; ++ks)
      bf[nf][ks] = *(const bf16x8*)(Bt + n*256 + ks*32 + lc*8);
  }
  #pragma unroll
  for (int p = 0; p < 8; ++p){
    int idx = (p*256 + tid)*8;
    int row = idx >> 8, col = idx & 255;
    int r = m0 + row;
    uint4 v = make_uint4(0u,0u,0u,0u);
    if (r < M) v = *(const uint4*)(H1 + r*H_DIM + col);
    unsigned short hb[8] = {(unsigned short)(v.x&0xffff),(unsigned short)(v.x>>16),
                            (unsigned short)(v.y&0xffff),(unsigned short)(v.y>>16),
                            (unsigned short)(v.z&0xffff),(unsigned short)(v.z>>16),
                            (unsigned short)(v.w&0xffff),(unsigned short)(v.w>>16)};
    unsigned outp[4];
    #pragma unroll
    for (int q = 0; q < 4; ++q){
      float f0 = fmaxf(colw[col+2*q]  *bf2f(hb[2*q])   + colb[col+2*q],   0.f);
      float f1 = fmaxf(colw[col+2*q+1]*bf2f(hb[2*q+1]) + colb[col+2*q+1], 0.f);
      outp[q] = (unsigned)f2bf(f0) | ((unsigned)f2bf(f1) << 16);
    }
    int o = (row*512 + col*2) ^ ((row & 7) << 4);
    *(uint4*)(smem + o) = make_uint4(outp[0],outp[1],outp[2],outp[3]);
  }
  __syncthreads();

  f32x4 acc[4][2] = {};
  #pragma unroll
  for (int ks = 0; ks < 8; ++ks){
    bf16x8 a[4];
    #pragma unroll
    for (int mf = 0; mf < 4; ++mf){
      int row = mf*16 + lr;
      int o = (row*512 + ks*64 + lc*16) ^ ((row & 7) << 4);
      a[mf] = *(const bf16x8*)(smem + o);
    }
    #pragma unroll
    for (int mf = 0; mf < 4; ++mf)
      #pragma unroll
      for (int nf = 0; nf < 2; ++nf)
        acc[mf][nf] = __builtin_amdgcn_mfma_f32_16x16x32_bf16(a[mf], bf[nf][ks], acc[mf][nf], 0, 0, 0);
  }

  float sA[2] = {0.f, 0.f}, sB[2] = {0.f, 0.f};   // per-nf column partial sum / sumsq
  #pragma unroll
  for (int mf = 0; mf < 4; ++mf){
    #pragma unroll
    for (int j = 0; j < 4; ++j){
      int r = m0 + mf*16 + lc*4 + j;
      if (r < M){
        #pragma unroll
        for (int nf = 0; nf < 2; ++nf){
          int col = wave*32 + nf*16 + lr;
          float v = X[r*C_DIM + col] + acc[mf][nf][j] + b2[col];
          X[r*C_DIM + col] = v;
          sA[nf] += v; sB[nf] += v*v;
        }
      }
    }
  }
  // reduce across lanes sharing lr (lc = 0..3)
  #pragma unroll
  for (int nf = 0; nf < 2; ++nf){
    sA[nf] += __shfl_xor(sA[nf], 16); sA[nf] += __shfl_xor(sA[nf], 32);
    sB[nf] += __shfl_xor(sB[nf], 16); sB[nf] += __shfl_xor(sB[nf], 32);
  }
  if (lane < 16){
    #pragma unroll
    for (int nf = 0; nf < 2; ++nf){
      int col = wave*32 + nf*16 + lr;
      part[col*NB + blockIdx.x]       = sA[nf];
      part[(128+col)*NB + blockIdx.x] = sB[nf];
    }
  }
}

// ---------------- final linear ----------------
__global__ void k_final(const float* __restrict__ X, const float* __restrict__ lw,
                        const float* __restrict__ lb, float* __restrict__ out, int N){
  int wave = threadIdx.x >> 6, lane = threadIdx.x & 63;
  int n = blockIdx.x*4 + wave;
  if (n >= N) return;
  float2 v = *(const float2*)(X + n*C_DIM + lane*2);
  float2 w = *(const float2*)(lw + lane*2);
  float s = v.x*w.x + v.y*w.y;
  #pragma unroll
  for (int o = 32; o; o >>= 1) s += __shfl_down(s, o);
  if (lane == 0) out[n] = s + lb[0];
}

extern "C" void kernel_launch(void* const* d_in, const int* in_sizes, int n_in,
                              void* d_out, int out_size, void* d_ws, size_t ws_size,
                              hipStream_t stream){
  const float* x    = (const float*)d_in[0];
  const int*   src  = (const int*)d_in[1];
  const int*   dst  = (const int*)d_in[2];
  const float* W1   = (const float*)d_in[3];
  const float* b1   = (const float*)d_in[4];
  const float* lnw  = (const float*)d_in[5];
  const float* lnb  = (const float*)d_in[6];
  const float* W2   = (const float*)d_in[7];
  const float* b2   = (const float*)d_in[8];
  const float* tpt  = (const float*)d_in[9];
  const float* gnw  = (const float*)d_in[10];
  const float* gnb  = (const float*)d_in[11];
  const float* gna  = (const float*)d_in[12];
  const float* linw = (const float*)d_in[13];
  const float* linb = (const float*)d_in[14];
  (void)n_in; (void)out_size; (void)ws_size;
  const int N = in_sizes[0] / C_DIM;
  const int E = in_sizes[1];
  float* out = (float*)d_out;

  const int gmw = (N + 63)/64;          // gemm blocks (64 rows each)
  const int S0  = (N + 127)/128;        // stat0 blocks
  const int NB  = gmw;                  // partial-stat stride (max of S0, gmw)

  char* wsp = (char*)d_ws; size_t off = 0;
  auto alloc = [&](size_t b)->char*{ char* p = wsp + off; off += (b + 255) & ~(size_t)255; return p; };
  int* cnt          = (int*)alloc((size_t)N*4);
  int* rp           = (int*)alloc((size_t)(N+1)*4);
  int* bsum         = (int*)alloc(1024);
  int* boff         = (int*)alloc(1024);
  float* gncoef     = (float*)alloc(1024);
  float* lncoef     = (float*)alloc(2048);
  float* lnpart     = (float*)alloc((size_t)gmw*2*4);
  float* part       = (float*)alloc((size_t)NB*256*4);   // column-major per-block GN partials
  int* csrc         = (int*)alloc((size_t)E*4);
  unsigned short* W1t = (unsigned short*)alloc((size_t)L_NUM*C_DIM*H_DIM*2);
  unsigned short* W2t = (unsigned short*)alloc((size_t)L_NUM*C_DIM*H_DIM*2);
  unsigned* g       = (unsigned*)alloc((size_t)N*C_DIM*2);   // bf16 [N][128]
  unsigned short* U = (unsigned short*)alloc((size_t)N*C_DIM*2);
  unsigned short* h1 = (unsigned short*)alloc((size_t)N*H_DIM*2);
  float* xc         = (float*)alloc((size_t)N*C_DIM*4);

  const int SB = (N + 255)/256;
  hipMemsetAsync(cnt, 0, (size_t)N*4, stream);
  k_hist<<<1024, 256, 0, stream>>>(dst, cnt, E);
  k_scan_local<<<SB, 256, 0, stream>>>(cnt, rp, bsum, N);
  k_scan_bsums<<<1, 256, 0, stream>>>(bsum, boff, SB);
  k_scan_add<<<SB, 256, 0, stream>>>(rp, boff, N, E);
  hipMemsetAsync(cnt, 0, (size_t)N*4, stream);
  k_scatter<<<1024, 256, 0, stream>>>(src, dst, rp, cnt, csrc, E);
  k_wconv<<<(L_NUM*C_DIM*H_DIM + 255)/256, 256, 0, stream>>>(W1, W2, W1t, W2t);
  hipMemcpyAsync(xc, x, (size_t)N*C_DIM*4, hipMemcpyDeviceToDevice, stream);
  k_stat0<<<S0, 256, 0, stream>>>(x, part, NB, N);

  for (int l = 0; l < L_NUM; ++l){
    int nb = (l == 0) ? S0 : gmw;
    k_gn_coef<<<128, 256, 0, stream>>>(part, NB, nb, gnw + l*C_DIM, gnb + l*C_DIM, gna + l*C_DIM, gncoef, N);
    k_gpre<<<(N*32 + 255)/256, 256, 0, stream>>>(xc, gncoef, g, N*32);
    k_agg<<<(N + 3)/4, 256, 0, stream>>>(g, rp, csrc, tpt, l, U, N);
    k_gemm1<<<gmw, 256, 0, stream>>>(U, W1t + (size_t)l*C_DIM*H_DIM, b1 + l*H_DIM, h1, lnpart, N);
    k_ln_coef<<<1, 256, 0, stream>>>(lnpart, gmw, lnw + l*H_DIM, lnb + l*H_DIM, lncoef, N);
    k_gemm2<<<gmw, 256, 0, stream>>>(h1, lncoef, W2t + (size_t)l*C_DIM*H_DIM, b2 + l*C_DIM, xc, part, NB, N);
  }
  k_final<<<(N + 3)/4, 256, 0, stream>>>(xc, linw, linb, out, N);
}

// Round 5
// 449.859 us; speedup vs baseline: 2.4211x; 1.0651x over previous
//
#include <hip/hip_runtime.h>

#define C_DIM 128
#define H_DIM 256
#define L_NUM 4

typedef __attribute__((ext_vector_type(8))) short bf16x8;
typedef __attribute__((ext_vector_type(4))) float f32x4;

__device__ __forceinline__ unsigned short f2bf(float f){
  unsigned u = __builtin_bit_cast(unsigned, f);
  u = u + 0x7FFFu + ((u >> 16) & 1u);   // round-to-nearest-even
  return (unsigned short)(u >> 16);
}
__device__ __forceinline__ float bf2f(unsigned short b){
  return __builtin_bit_cast(float, ((unsigned)b) << 16);
}

// ---------------- CSR build ----------------
__global__ void k_hist(const int* __restrict__ dst, int* __restrict__ cnt, int E){
  for (int e = blockIdx.x*blockDim.x + threadIdx.x; e < E; e += gridDim.x*blockDim.x)
    atomicAdd(cnt + dst[e], 1);
}

__global__ void k_scan_local(const int* __restrict__ cnt, int* __restrict__ rp,
                             int* __restrict__ bsum, int N){
  __shared__ int tmp[256];
  int t = threadIdx.x; int i = blockIdx.x*256 + t;
  int v = (i < N) ? cnt[i] : 0;
  tmp[t] = v; __syncthreads();
  for (int off = 1; off < 256; off <<= 1){
    int x = (t >= off) ? tmp[t-off] : 0; __syncthreads();
    tmp[t] += x; __syncthreads();
  }
  if (i < N) rp[i] = tmp[t] - v;              // exclusive within block
  if (t == 255) bsum[blockIdx.x] = tmp[t];
}

__global__ void k_scan_bsums(const int* __restrict__ bsum, int* __restrict__ boff, int nb){
  __shared__ int tmp[256];
  int t = threadIdx.x;
  int v = (t < nb) ? bsum[t] : 0;
  tmp[t] = v; __syncthreads();
  for (int off = 1; off < 256; off <<= 1){
    int x = (t >= off) ? tmp[t-off] : 0; __syncthreads();
    tmp[t] += x; __syncthreads();
  }
  if (t < nb) boff[t] = tmp[t] - v;           // exclusive
}

__global__ void k_scan_add(int* __restrict__ rp, const int* __restrict__ boff, int N, int E){
  int i = blockIdx.x*256 + threadIdx.x;
  if (i < N) rp[i] += boff[blockIdx.x];
  if (i == 0) rp[N] = E;
}

__global__ void k_scatter(const int* __restrict__ src, const int* __restrict__ dst,
                          const int* __restrict__ rp, int* __restrict__ cnt,
                          int* __restrict__ csrc, int E){
  for (int e = blockIdx.x*blockDim.x + threadIdx.x; e < E; e += gridDim.x*blockDim.x){
    int d = dst[e];
    int pos = rp[d] + atomicAdd(cnt + d, 1);
    csrc[pos] = src[e];
  }
}

// ---------------- weight transpose+convert ----------------
__global__ void k_wconv(const float* __restrict__ W1, const float* __restrict__ W2,
                        unsigned short* __restrict__ W1t, unsigned short* __restrict__ W2t){
  int i = blockIdx.x*blockDim.x + threadIdx.x;
  if (i >= L_NUM*C_DIM*H_DIM) return;
  int l = i >> 15, r = i & 32767;
  { int k = r >> 8, n = r & 255;  W1t[l*32768 + n*128 + k] = f2bf(W1[i]); }
  { int k = r >> 7, n = r & 127;  W2t[l*32768 + n*256 + k] = f2bf(W2[i]); }
}

// ---------------- layer-0 per-channel partial stats (column-major part[stat][NB]) --------
__global__ void k_stat0(const float* __restrict__ X, float* __restrict__ part, int NB, int N){
  int t = threadIdx.x; int c = t & 127; int half = t >> 7;
  int r0 = blockIdx.x*128, rend = min(r0 + 128, N);
  float s = 0.f, s2 = 0.f;
  for (int r = r0 + half; r < rend; r += 2){
    float v = X[r*C_DIM + c]; s += v; s2 += v*v;
  }
  __shared__ float a1[256], a2[256];
  a1[t] = s; a2[t] = s2; __syncthreads();
  if (t < 128){
    part[t*NB + blockIdx.x]       = a1[t] + a1[t+128];
    part[(128+t)*NB + blockIdx.x] = a2[t] + a2[t+128];
  }
}

// ---------------- graph norm: reduce partials + coef, one block per channel ----------------
__global__ void k_gn_coef(const float* __restrict__ part, int NB, int nb,
                          const float* __restrict__ gw, const float* __restrict__ gb,
                          const float* __restrict__ ga, float* __restrict__ coef, int N){
  int c = blockIdx.x;       // 0..127
  int t = threadIdx.x;      // 256
  float s = 0.f, s2 = 0.f;
  for (int i = t; i < nb; i += 256){
    s  += part[c*NB + i];
    s2 += part[(128+c)*NB + i];
  }
  __shared__ float sh1[256], sh2[256];
  sh1[t] = s; sh2[t] = s2; __syncthreads();
  for (int off = 128; off; off >>= 1){
    if (t < off){ sh1[t] += sh1[t+off]; sh2[t] += sh2[t+off]; }
    __syncthreads();
  }
  if (t == 0){
    float inv = 1.f/(float)N;
    float mean = sh1[0]*inv;
    float am = ga[c]*mean;
    float var = sh2[0]*inv - 2.f*am*mean + am*am;   // E[(x - a*mean)^2]
    float scale = gw[c] * rsqrtf(var + 1e-5f);
    coef[c] = scale;
    coef[128+c] = gb[c] - scale*am;
  }
}

// ---------------- g = relu(affine(x)) in bf16 ----------------
__global__ void k_gpre(const float* __restrict__ X, const float* __restrict__ coef,
                       unsigned* __restrict__ G2, int total4){
  int i = blockIdx.x*blockDim.x + threadIdx.x;
  if (i >= total4) return;
  int c4 = i & 31;
  float4 x = ((const float4*)X)[i];
  float4 A = ((const float4*)coef)[c4];
  float4 B = ((const float4*)coef)[32 + c4];
  float o0 = fmaxf(A.x*x.x + B.x, 0.f);
  float o1 = fmaxf(A.y*x.y + B.y, 0.f);
  float o2 = fmaxf(A.z*x.z + B.z, 0.f);
  float o3 = fmaxf(A.w*x.w + B.w, 0.f);
  uint2 pk = make_uint2((unsigned)f2bf(o0) | ((unsigned)f2bf(o1) << 16),
                        (unsigned)f2bf(o2) | ((unsigned)f2bf(o3) << 16));
  ((uint2*)G2)[i] = pk;
}

// ---------------- softmax aggregation, max-free; shfl-broadcast edge indices -------------
__global__ void k_agg(const unsigned* __restrict__ G, const int* __restrict__ rp,
                      const int* __restrict__ csrc, const float* __restrict__ tptr, int l,
                      unsigned short* __restrict__ U, int N){
  int wave = threadIdx.x >> 6, lane = threadIdx.x & 63;
  int n = blockIdx.x*4 + wave;
  if (n >= N) return;
  float tv = tptr[l];
  int jb = rp[n], je = rp[n+1];
  float d0 = 0.f, d1 = 0.f, s0 = 0.f, s1 = 0.f;

  #define EDGE(uu) { \
    float msg0 = bf2f((unsigned short)((uu) & 0xffff)) + 1e-7f; \
    float msg1 = bf2f((unsigned short)((uu) >> 16)) + 1e-7f; \
    float e0 = __expf(fminf(tv*msg0, 60.f)); \
    float e1 = __expf(fminf(tv*msg1, 60.f)); \
    d0 += e0; d1 += e1; s0 += msg0*e0; s1 += msg1*e1; }

  for (int base = jb; base < je; base += 64){
    int cnt = min(64, je - base);
    int myidx = (base + lane < je) ? csrc[base + lane] : 0;
    int jj = 0;
    for (; jj + 3 < cnt; jj += 4){
      int i0 = __shfl(myidx, jj);
      int i1 = __shfl(myidx, jj+1);
      int i2 = __shfl(myidx, jj+2);
      int i3 = __shfl(myidx, jj+3);
      unsigned u0 = G[i0*64 + lane];
      unsigned u1 = G[i1*64 + lane];
      unsigned u2 = G[i2*64 + lane];
      unsigned u3 = G[i3*64 + lane];
      EDGE(u0); EDGE(u1); EDGE(u2); EDGE(u3);
    }
    for (; jj < cnt; ++jj){
      unsigned u = G[__shfl(myidx, jj)*64 + lane];
      EDGE(u);
    }
  }
  #undef EDGE

  unsigned uo = G[n*64 + lane];
  float g0 = bf2f((unsigned short)(uo & 0xffff));
  float g1 = bf2f((unsigned short)(uo >> 16));
  float u0 = s0/(d0 + 1e-16f) + g0;
  float u1 = s1/(d1 + 1e-16f) + g1;
  unsigned pk = (unsigned)f2bf(u0) | ((unsigned)f2bf(u1) << 16);
  *(unsigned*)(U + n*C_DIM + lane*2) = pk;
}

// ---------------- GEMM1: h1(bf16) = U(bf16)[M,128] @ W1t^T + b1 ; per-block LN partials ----
__global__ void k_gemm1(const unsigned short* __restrict__ A, const unsigned short* __restrict__ Bt,
                        const float* __restrict__ b1, unsigned short* __restrict__ H1,
                        float* __restrict__ part, int M){
  __shared__ __align__(16) char smem[64*256];   // 64 rows x 128 bf16 (256B rows), swizzled
  __shared__ float rbuf[8];
  const int tid = threadIdx.x;
  const int m0 = blockIdx.x * 64;
  const int wave = tid >> 6, lane = tid & 63;
  const int lr = lane & 15, lc = lane >> 4;

  bf16x8 bf[4][4];
  #pragma unroll
  for (int nf = 0; nf < 4; ++nf){
    int n = wave*64 + nf*16 + lr;
    #pragma unroll
    for (int ks = 0; ks < 4; ++ks)
      bf[nf][ks] = *(const bf16x8*)(Bt + n*128 + ks*32 + lc*8);
  }
  #pragma unroll
  for (int p = 0; p < 4; ++p){
    int idx = p*256 + tid;
    int row = idx >> 4, ch = idx & 15;
    int r = m0 + row;
    uint4 v = make_uint4(0u,0u,0u,0u);
    if (r < M) v = *(const uint4*)(A + r*128 + ch*8);
    int o = (row*256 + ch*16) ^ ((row & 7) << 4);
    *(uint4*)(smem + o) = v;
  }
  __syncthreads();

  f32x4 acc[4][4] = {};
  #pragma unroll
  for (int ks = 0; ks < 4; ++ks){
    bf16x8 a[4];
    #pragma unroll
    for (int mf = 0; mf < 4; ++mf){
      int row = mf*16 + lr;
      int o = (row*256 + ks*64 + lc*16) ^ ((row & 7) << 4);
      a[mf] = *(const bf16x8*)(smem + o);
    }
    #pragma unroll
    for (int mf = 0; mf < 4; ++mf)
      #pragma unroll
      for (int nf = 0; nf < 4; ++nf)
        acc[mf][nf] = __builtin_amdgcn_mfma_f32_16x16x32_bf16(a[mf], bf[nf][ks], acc[mf][nf], 0, 0, 0);
  }

  float s1 = 0.f, s2 = 0.f;
  #pragma unroll
  for (int mf = 0; mf < 4; ++mf){
    #pragma unroll
    for (int j = 0; j < 4; ++j){
      int r = m0 + mf*16 + lc*4 + j;
      if (r < M){
        #pragma unroll
        for (int nf = 0; nf < 4; ++nf){
          int col = wave*64 + nf*16 + lr;
          float v = acc[mf][nf][j] + b1[col];
          H1[r*H_DIM + col] = f2bf(v);
          s1 += v; s2 += v*v;
        }
      }
    }
  }
  #pragma unroll
  for (int o = 32; o; o >>= 1){ s1 += __shfl_down(s1, o); s2 += __shfl_down(s2, o); }
  if (lane == 0){ rbuf[wave] = s1; rbuf[4 + wave] = s2; }
  __syncthreads();
  if (tid == 0)
    part[blockIdx.x*2]     = rbuf[0]+rbuf[1]+rbuf[2]+rbuf[3];
  if (tid == 1)
    part[blockIdx.x*2 + 1] = rbuf[4]+rbuf[5]+rbuf[6]+rbuf[7];
}

// ---- GEMM2: x_out = x_in + relu(LN(H1))(bf16) @ W2t^T + b2 ; LN coef block-local;
//      writes next-layer GN partials; last layer: fused final linear to out --------------
__global__ void k_gemm2(const unsigned short* __restrict__ H1,
                        const float* __restrict__ lnpart, int nparts,
                        const float* __restrict__ lnw, const float* __restrict__ lnb,
                        const unsigned short* __restrict__ Bt, const float* __restrict__ b2,
                        const float* __restrict__ Xin, float* __restrict__ Xout,
                        float* __restrict__ part, int NB,
                        const float* __restrict__ lw, const float* __restrict__ lb,
                        float* __restrict__ out, int M){
  __shared__ __align__(16) char smem[64*512];   // 64 rows x 256 bf16 (512B rows), swizzled
  __shared__ float red1[256], red2[256];
  __shared__ float colw[256], colb[256];
  __shared__ float rowdot[64];
  const int tid = threadIdx.x;
  const int m0 = blockIdx.x * 64;
  const int wave = tid >> 6, lane = tid & 63;
  const int lr = lane & 15, lc = lane >> 4;
  const bool last = (lw != nullptr);

  // ---- LN coefficients (block-local deterministic reduction of lnpart) ----
  {
    float s1 = 0.f, s2 = 0.f;
    for (int i = tid; i < nparts; i += 256){ s1 += lnpart[2*i]; s2 += lnpart[2*i+1]; }
    red1[tid] = s1; red2[tid] = s2; __syncthreads();
    for (int o = 128; o; o >>= 1){
      if (tid < o){ red1[tid] += red1[tid+o]; red2[tid] += red2[tid+o]; }
      __syncthreads();
    }
    double NH = (double)M * (double)H_DIM;
    double mean = (double)red1[0] / NH;
    double var = (double)red2[0] / NH - mean*mean;
    double sd = sqrt(var > 0.0 ? var : 0.0);
    float denom = (float)sd + 1e-5f;
    float wv = lnw[tid] / denom;
    colw[tid] = wv;
    colb[tid] = lnb[tid] - (float)mean * wv;
    if (tid < 64) rowdot[tid] = 0.f;
    __syncthreads();
  }

  bf16x8 bf[2][8];
  #pragma unroll
  for (int nf = 0; nf < 2; ++nf){
    int n = wave*32 + nf*16 + lr;
    #pragma unroll
    for (int ks = 0; ks < 8; ++ks)
      bf[nf][ks] = *(const bf16x8*)(Bt + n*256 + ks*32 + lc*8);
  }
  #pragma unroll
  for (int p = 0; p < 8; ++p){
    int idx = (p*256 + tid)*8;
    int row = idx >> 8, col = idx & 255;
    int r = m0 + row;
    uint4 v = make_uint4(0u,0u,0u,0u);
    if (r < M) v = *(const uint4*)(H1 + r*H_DIM + col);
    unsigned short hb[8] = {(unsigned short)(v.x&0xffff),(unsigned short)(v.x>>16),
                            (unsigned short)(v.y&0xffff),(unsigned short)(v.y>>16),
                            (unsigned short)(v.z&0xffff),(unsigned short)(v.z>>16),
                            (unsigned short)(v.w&0xffff),(unsigned short)(v.w>>16)};
    unsigned outp[4];
    #pragma unroll
    for (int q = 0; q < 4; ++q){
      float f0 = fmaxf(colw[col+2*q]  *bf2f(hb[2*q])   + colb[col+2*q],   0.f);
      float f1 = fmaxf(colw[col+2*q+1]*bf2f(hb[2*q+1]) + colb[col+2*q+1], 0.f);
      outp[q] = (unsigned)f2bf(f0) | ((unsigned)f2bf(f1) << 16);
    }
    int o = (row*512 + col*2) ^ ((row & 7) << 4);
    *(uint4*)(smem + o) = make_uint4(outp[0],outp[1],outp[2],outp[3]);
  }
  __syncthreads();

  f32x4 acc[4][2] = {};
  #pragma unroll
  for (int ks = 0; ks < 8; ++ks){
    bf16x8 a[4];
    #pragma unroll
    for (int mf = 0; mf < 4; ++mf){
      int row = mf*16 + lr;
      int o = (row*512 + ks*64 + lc*16) ^ ((row & 7) << 4);
      a[mf] = *(const bf16x8*)(smem + o);
    }
    #pragma unroll
    for (int mf = 0; mf < 4; ++mf)
      #pragma unroll
      for (int nf = 0; nf < 2; ++nf)
        acc[mf][nf] = __builtin_amdgcn_mfma_f32_16x16x32_bf16(a[mf], bf[nf][ks], acc[mf][nf], 0, 0, 0);
  }

  float sA[2] = {0.f, 0.f}, sB[2] = {0.f, 0.f};
  #pragma unroll
  for (int mf = 0; mf < 4; ++mf){
    #pragma unroll
    for (int j = 0; j < 4; ++j){
      int r = m0 + mf*16 + lc*4 + j;
      if (r < M){
        float p = 0.f;
        #pragma unroll
        for (int nf = 0; nf < 2; ++nf){
          int col = wave*32 + nf*16 + lr;
          float v = Xin[r*C_DIM + col] + acc[mf][nf][j] + b2[col];
          if (!last){
            Xout[r*C_DIM + col] = v;
            sA[nf] += v; sB[nf] += v*v;
          } else {
            p += v * lw[col];
          }
        }
        if (last){
          p += __shfl_xor(p, 1); p += __shfl_xor(p, 2);
          p += __shfl_xor(p, 4); p += __shfl_xor(p, 8);
          if (lr == 0) atomicAdd(&rowdot[r - m0], p);
        }
      }
    }
  }
  if (!last){
    #pragma unroll
    for (int nf = 0; nf < 2; ++nf){
      sA[nf] += __shfl_xor(sA[nf], 16); sA[nf] += __shfl_xor(sA[nf], 32);
      sB[nf] += __shfl_xor(sB[nf], 16); sB[nf] += __shfl_xor(sB[nf], 32);
    }
    if (lane < 16){
      #pragma unroll
      for (int nf = 0; nf < 2; ++nf){
        int col = wave*32 + nf*16 + lr;
        part[col*NB + blockIdx.x]       = sA[nf];
        part[(128+col)*NB + blockIdx.x] = sB[nf];
      }
    }
  } else {
    __syncthreads();
    if (tid < 64 && m0 + tid < M) out[m0 + tid] = rowdot[tid] + lb[0];
  }
}

extern "C" void kernel_launch(void* const* d_in, const int* in_sizes, int n_in,
                              void* d_out, int out_size, void* d_ws, size_t ws_size,
                              hipStream_t stream){
  const float* x    = (const float*)d_in[0];
  const int*   src  = (const int*)d_in[1];
  const int*   dst  = (const int*)d_in[2];
  const float* W1   = (const float*)d_in[3];
  const float* b1   = (const float*)d_in[4];
  const float* lnw  = (const float*)d_in[5];
  const float* lnb  = (const float*)d_in[6];
  const float* W2   = (const float*)d_in[7];
  const float* b2   = (const float*)d_in[8];
  const float* tpt  = (const float*)d_in[9];
  const float* gnw  = (const float*)d_in[10];
  const float* gnb  = (const float*)d_in[11];
  const float* gna  = (const float*)d_in[12];
  const float* linw = (const float*)d_in[13];
  const float* linb = (const float*)d_in[14];
  (void)n_in; (void)out_size; (void)ws_size;
  const int N = in_sizes[0] / C_DIM;
  const int E = in_sizes[1];
  float* out = (float*)d_out;

  const int gmw = (N + 63)/64;          // gemm blocks (64 rows each)
  const int S0  = (N + 127)/128;        // stat0 blocks
  const int NB  = gmw;                  // partial-stat stride

  char* wsp = (char*)d_ws; size_t off = 0;
  auto alloc = [&](size_t b)->char*{ char* p = wsp + off; off += (b + 255) & ~(size_t)255; return p; };
  int* cnt          = (int*)alloc((size_t)N*4);
  int* rp           = (int*)alloc((size_t)(N+1)*4);
  int* bsum         = (int*)alloc(1024);
  int* boff         = (int*)alloc(1024);
  float* gncoef     = (float*)alloc(1024);
  float* lnpart     = (float*)alloc((size_t)gmw*2*4);
  float* part       = (float*)alloc((size_t)NB*256*4);   // column-major per-block GN partials
  int* csrc         = (int*)alloc((size_t)E*4);
  unsigned short* W1t = (unsigned short*)alloc((size_t)L_NUM*C_DIM*H_DIM*2);
  unsigned short* W2t = (unsigned short*)alloc((size_t)L_NUM*C_DIM*H_DIM*2);
  unsigned* g       = (unsigned*)alloc((size_t)N*C_DIM*2);   // bf16 [N][128]
  unsigned short* U = (unsigned short*)alloc((size_t)N*C_DIM*2);
  unsigned short* h1 = (unsigned short*)alloc((size_t)N*H_DIM*2);
  float* xc         = (float*)alloc((size_t)N*C_DIM*4);

  const int SB = (N + 255)/256;
  hipMemsetAsync(cnt, 0, (size_t)N*4, stream);
  k_hist<<<1024, 256, 0, stream>>>(dst, cnt, E);
  k_scan_local<<<SB, 256, 0, stream>>>(cnt, rp, bsum, N);
  k_scan_bsums<<<1, 256, 0, stream>>>(bsum, boff, SB);
  k_scan_add<<<SB, 256, 0, stream>>>(rp, boff, N, E);
  hipMemsetAsync(cnt, 0, (size_t)N*4, stream);
  k_scatter<<<1024, 256, 0, stream>>>(src, dst, rp, cnt, csrc, E);
  k_wconv<<<(L_NUM*C_DIM*H_DIM + 255)/256, 256, 0, stream>>>(W1, W2, W1t, W2t);
  k_stat0<<<S0, 256, 0, stream>>>(x, part, NB, N);

  for (int l = 0; l < L_NUM; ++l){
    int nb = (l == 0) ? S0 : gmw;
    const float* Xin = (l == 0) ? x : xc;
    bool lastL = (l == L_NUM - 1);
    k_gn_coef<<<128, 256, 0, stream>>>(part, NB, nb, gnw + l*C_DIM, gnb + l*C_DIM, gna + l*C_DIM, gncoef, N);
    k_gpre<<<(N*32 + 255)/256, 256, 0, stream>>>(Xin, gncoef, g, N*32);
    k_agg<<<(N + 3)/4, 256, 0, stream>>>(g, rp, csrc, tpt, l, U, N);
    k_gemm1<<<gmw, 256, 0, stream>>>(U, W1t + (size_t)l*C_DIM*H_DIM, b1 + l*H_DIM, h1, lnpart, N);
    k_gemm2<<<gmw, 256, 0, stream>>>(h1, lnpart, gmw, lnw + l*H_DIM, lnb + l*H_DIM,
                                     W2t + (size_t)l*C_DIM*H_DIM, b2 + l*C_DIM,
                                     Xin, xc, part, NB,
                                     lastL ? linw : nullptr, linb, out, N);
  }
}